// Round 1
// baseline (386.747 us; speedup 1.0000x reference)
//
#include <hip/hip_runtime.h>
#include <hip/hip_bf16.h>

typedef unsigned short u16;
typedef __attribute__((ext_vector_type(4))) float f32x4;
typedef __attribute__((ext_vector_type(8))) short v8s;

#define NB 4
#define NT 8
#define NN 128
#define ND 512
#define NH 8
#define NDH 64
#define NS 1024

static __device__ __forceinline__ u16 f2b(float f) {
  __hip_bfloat16 h = __float2bfloat16(f);
  return *reinterpret_cast<u16*>(&h);
}
static __device__ __forceinline__ float b2f(u16 u) {
  __hip_bfloat16 h;
  *reinterpret_cast<u16*>(&h) = u;
  return __bfloat162float(h);
}

// ---------------- fp32 -> bf16 cast (vectorized, 8 elems/thread) ----------------
__global__ void __launch_bounds__(256) cast_kernel(const float* __restrict__ src,
                                                   u16* __restrict__ dst, int n8) {
  int i = blockIdx.x * blockDim.x + threadIdx.x;
  if (i >= n8) return;
  const float4* s4 = reinterpret_cast<const float4*>(src) + (size_t)i * 2;
  float4 a = s4[0], b = s4[1];
  u16 r[8] = {f2b(a.x), f2b(a.y), f2b(a.z), f2b(a.w),
              f2b(b.x), f2b(b.y), f2b(b.z), f2b(b.w)};
  *reinterpret_cast<v8s*>(dst + (size_t)i * 8) = *reinterpret_cast<v8s*>(r);
}

// ---------------- weight transpose + cast: W (K x N) f32 -> Wt (N x K) bf16 ------
__global__ void __launch_bounds__(256) transpose_cast_kernel(const float* __restrict__ W,
                                                             u16* __restrict__ Wt,
                                                             int K, int N) {
  __shared__ float t[32][33];
  int tx = threadIdx.x & 31, ty = threadIdx.x >> 5;
  int kb = blockIdx.y * 32, nb = blockIdx.x * 32;
#pragma unroll
  for (int i = 0; i < 4; i++) {
    int r = ty + i * 8;
    t[r][tx] = W[(size_t)(kb + r) * N + nb + tx];
  }
  __syncthreads();
#pragma unroll
  for (int i = 0; i < 4; i++) {
    int r = ty + i * 8;
    Wt[(size_t)(nb + r) * K + kb + tx] = f2b(t[tx][r]);
  }
}

// ---------------- extract coords (B,S,3) from x_0[..., :3] -----------------------
__global__ void coords_kernel(const float* __restrict__ x0, float* __restrict__ c, int n) {
  int i = blockIdx.x * blockDim.x + threadIdx.x;
  if (i < n) {
    c[i * 3 + 0] = x0[(size_t)i * ND + 0];
    c[i * 3 + 1] = x0[(size_t)i * ND + 1];
    c[i * 3 + 2] = x0[(size_t)i * ND + 2];
  }
}

// ---------------- bf16 MFMA GEMM, C = A(MxK) @ Wt(NxK)^T + bias ------------------
// mode 0: q-proj epilogue  -> RoPE, write (B,H,S,DH) bf16
// mode 1: kv-proj epilogue -> n<512: RoPE K -> (F,B,H,S,DH); n>=512: V -> (F,B,H,DH,S)
// mode 2: out-proj         -> +bo, write f32 d_out (B*S, 512)
__global__ void __launch_bounds__(256) gemm_kernel(const u16* __restrict__ A,
                                                   const u16* __restrict__ Wt,
                                                   const float* __restrict__ bias,
                                                   u16* __restrict__ outK,
                                                   u16* __restrict__ outV,
                                                   float* __restrict__ outF,
                                                   int M, int N, int K, int mode, int f) {
  __shared__ u16 At[64 * 40];  // 64 rows x 32 cols, padded to 40 (80B row: 2-way max)
  __shared__ u16 Bt[64 * 40];
  int nt = N >> 6;
  int by = blockIdx.x / nt, bx = blockIdx.x % nt;
  int tid = threadIdx.x;
  int lane = tid & 63, wave = tid >> 6;
  int g = lane >> 4, li = lane & 15;
  int wm = (wave & 1) * 32, wn = (wave >> 1) * 32;
  f32x4 acc[2][2] = {};
  int sr = tid >> 2, sc = tid & 3;
  const u16* Arow = A + (size_t)(by * 64 + sr) * K + sc * 8;
  const u16* Brow = Wt + (size_t)(bx * 64 + sr) * K + sc * 8;
  for (int kb = 0; kb < K; kb += 32) {
    v8s av = *reinterpret_cast<const v8s*>(Arow + kb);
    v8s bv = *reinterpret_cast<const v8s*>(Brow + kb);
    __syncthreads();  // WAR: previous iteration's fragment reads done
    *reinterpret_cast<v8s*>(&At[sr * 40 + sc * 8]) = av;
    *reinterpret_cast<v8s*>(&Bt[sr * 40 + sc * 8]) = bv;
    __syncthreads();
#pragma unroll
    for (int mi = 0; mi < 2; mi++) {
      v8s a = *reinterpret_cast<v8s*>(&At[(wm + mi * 16 + li) * 40 + g * 8]);
#pragma unroll
      for (int ni = 0; ni < 2; ni++) {
        v8s b = *reinterpret_cast<v8s*>(&Bt[(wn + ni * 16 + li) * 40 + g * 8]);
        acc[mi][ni] = __builtin_amdgcn_mfma_f32_16x16x32_bf16(a, b, acc[mi][ni], 0, 0, 0);
      }
    }
  }
  // epilogue: D[m = 4*g + r (+16*mi+wm)][n = li (+16*ni+wn)]
#pragma unroll
  for (int mi = 0; mi < 2; mi++)
#pragma unroll
    for (int ni = 0; ni < 2; ni++)
#pragma unroll
      for (int r = 0; r < 4; r++) {
        int mrow = by * 64 + wm + mi * 16 + 4 * g + r;
        int n = bx * 64 + wn + ni * 16 + li;
        float val = acc[mi][ni][r] + bias[n];
        if (mode == 2) {
          outF[(size_t)mrow * N + n] = val;
        } else {
          int b = mrow >> 10, s = mrow & 1023;
          bool isv = (mode == 1) && (n >= 512);
          float partner = __shfl_xor(val, 1);  // uniform control flow: exchange first
          if (!isv) {
            int d = n & 63, h = (n & 511) >> 6;
            int j = d >> 1;
            float freq = __expf(-(float)j * 0.21586735246819178f);  // 1000^(-j/32)
            float ang = (float)(s >> 7) * freq;
            float sn, cs;
            sincosf(ang, &sn, &cs);
            float res = (n & 1) ? (partner * sn + val * cs) : (val * cs - partner * sn);
            size_t idx;
            if (mode == 0)
              idx = ((size_t)(b * NH + h) * NS + s) * NDH + d;
            else
              idx = ((size_t)((f * NB + b) * NH + h) * NS + s) * NDH + d;
            outK[idx] = f2b(res);
          } else {
            int vd = n - 512;
            int h = vd >> 6, d = vd & 63;
            outV[((size_t)((f * NB + b) * NH + h) * NDH + d) * NS + s] = f2b(val);
          }
        }
      }
}

// ---------------- SH-bias: (b,q,k) -> MLP 4->16->16->8, write (B,H,S,S) bf16 -----
__global__ void __launch_bounds__(256) bias_kernel(const float* __restrict__ coords,
                                                   const float* __restrict__ W1,
                                                   const float* __restrict__ b1,
                                                   const float* __restrict__ W2,
                                                   const float* __restrict__ b2,
                                                   const float* __restrict__ W3,
                                                   const float* __restrict__ b3,
                                                   u16* __restrict__ biasT) {
  __shared__ float w[488];  // W1[64] b1@64 W2@80 b2@336 W3@352 b3@480
  int tid = threadIdx.x;
  if (tid < 64) w[tid] = W1[tid];
  if (tid < 16) { w[64 + tid] = b1[tid]; w[336 + tid] = b2[tid]; }
  w[80 + tid] = W2[tid];
  if (tid < 128) w[352 + tid] = W3[tid];
  if (tid < 8) w[480 + tid] = b3[tid];
  __syncthreads();
  int blk = blockIdx.x;
  int kb = blk & 3, q = (blk >> 2) & 1023, b = blk >> 12;
  int kk = kb * 256 + tid;
  float cqx = coords[(size_t)(b * NS + q) * 3 + 0];
  float cqy = coords[(size_t)(b * NS + q) * 3 + 1];
  float cqz = coords[(size_t)(b * NS + q) * 3 + 2];
  float rx = cqx - coords[(size_t)(b * NS + kk) * 3 + 0];
  float ry = cqy - coords[(size_t)(b * NS + kk) * 3 + 1];
  float rz = cqz - coords[(size_t)(b * NS + kk) * 3 + 2];
  float nrm = sqrtf(rx * rx + ry * ry + rz * rz);
  float inv = 1.0f / (nrm + 1e-6f);
  const float Y1 = 0.4886025119029199f;
  const float Y0 = 0.28209479177387814f;
  float shy = Y1 * ry * inv, shz = Y1 * rz * inv, shx = Y1 * rx * inv;
  float h1[16], h2[16];
#pragma unroll
  for (int j = 0; j < 16; j++) {
    float a = Y0 * w[j] + shy * w[16 + j] + shz * w[32 + j] + shx * w[48 + j] + w[64 + j];
    h1[j] = a / (1.0f + __expf(-a));
  }
#pragma unroll
  for (int j = 0; j < 16; j++) {
    float a = w[336 + j];
#pragma unroll
    for (int i = 0; i < 16; i++) a += h1[i] * w[80 + i * 16 + j];
    h2[j] = a / (1.0f + __expf(-a));
  }
#pragma unroll
  for (int hh = 0; hh < 8; hh++) {
    float a = w[480 + hh];
#pragma unroll
    for (int i = 0; i < 16; i++) a += h2[i] * w[352 + i * 8 + hh];
    biasT[((size_t)(b * NH + hh) * NS + q) * NS + kk] = f2b(a);
  }
}

// ---------------- fused 3-feature flash attention (MFMA 16x16x32 bf16) -----------
// grid: B*H*(S/64); block 256 = 4 waves; wave owns 16 q-rows, full K-loop.
__global__ void __launch_bounds__(256) attn_kernel(const u16* __restrict__ q,
                                                   const u16* __restrict__ kmat,
                                                   const u16* __restrict__ vt,
                                                   const u16* __restrict__ biasT,
                                                   const float* __restrict__ fw,
                                                   const float* __restrict__ denom,
                                                   u16* __restrict__ attno) {
  __shared__ u16 plds[4][512];  // per-wave 16x32 bf16 P-tile, XOR-swizzled
  int blk = blockIdx.x;
  int bh = blk >> 4, qt = blk & 15;
  int h = bh & 7;
  int lane = threadIdx.x & 63, wave = threadIdx.x >> 6;
  int g = lane >> 4, li = lane & 15;
  int qw = qt * 64 + wave * 16;

  float f0 = fw[0], f1 = fw[1], f2v = fw[2];
  float mx = fmaxf(f0, fmaxf(f1, f2v));
  float e0 = __expf(f0 - mx), e1 = __expf(f1 - mx), e2 = __expf(f2v - mx);
  float esum = e0 + e1 + e2;
  float gates[3] = {e0 / esum, e1 / esum, e2 / esum};
  float invd = 1.0f / denom[h];

  const u16* qbase = q + ((size_t)bh * NS + qw + li) * NDH + g * 8;
  v8s qa0 = *reinterpret_cast<const v8s*>(qbase);
  v8s qa1 = *reinterpret_cast<const v8s*>(qbase + 32);

  float mr[3][4], lr[3][4];
  f32x4 o[3][4];
  f32x4 zero = {0.f, 0.f, 0.f, 0.f};
#pragma unroll
  for (int ff = 0; ff < 3; ff++)
#pragma unroll
    for (int r = 0; r < 4; r++) { mr[ff][r] = -3.0e38f; lr[ff][r] = 0.f; }
#pragma unroll
  for (int ff = 0; ff < 3; ff++)
#pragma unroll
    for (int ni = 0; ni < 4; ni++) o[ff][ni] = zero;

  const u16* bbase = biasT + ((size_t)bh * NS + qw + 4 * g) * NS;
  u16* pw = plds[wave];

  for (int k0 = 0; k0 < NS; k0 += 32) {
    float bb[2][4];
#pragma unroll
    for (int kks = 0; kks < 2; kks++)
#pragma unroll
      for (int r = 0; r < 4; r++)
        bb[kks][r] = b2f(bbase[(size_t)r * NS + k0 + kks * 16 + li]);
#pragma unroll
    for (int ff = 0; ff < 3; ff++) {
      const u16* kbp = kmat + ((size_t)(ff * 32 + bh) * NS) * NDH;
      float pv[2][4];
#pragma unroll
      for (int kks = 0; kks < 2; kks++) {
        const u16* krow = kbp + (size_t)(k0 + kks * 16 + li) * NDH + g * 8;
        v8s kb0 = *reinterpret_cast<const v8s*>(krow);
        v8s kb1 = *reinterpret_cast<const v8s*>(krow + 32);
        f32x4 sc = __builtin_amdgcn_mfma_f32_16x16x32_bf16(qa0, kb0, zero, 0, 0, 0);
        sc = __builtin_amdgcn_mfma_f32_16x16x32_bf16(qa1, kb1, sc, 0, 0, 0);
#pragma unroll
        for (int r = 0; r < 4; r++) pv[kks][r] = sc[r] * invd + bb[kks][r];
      }
      float al[4];
#pragma unroll
      for (int r = 0; r < 4; r++) {
        float rm = fmaxf(pv[0][r], pv[1][r]);
        rm = fmaxf(rm, __shfl_xor(rm, 1));
        rm = fmaxf(rm, __shfl_xor(rm, 2));
        rm = fmaxf(rm, __shfl_xor(rm, 4));
        rm = fmaxf(rm, __shfl_xor(rm, 8));
        float nm = fmaxf(mr[ff][r], rm);
        al[r] = __expf(mr[ff][r] - nm);
        mr[ff][r] = nm;
        float p0 = __expf(pv[0][r] - nm);
        float p1 = __expf(pv[1][r] - nm);
        lr[ff][r] = lr[ff][r] * al[r] + p0 + p1;  // per-lane partial, reduced at end
        pv[0][r] = p0;
        pv[1][r] = p1;
      }
      // P -> LDS (transpose to A-fragment layout), XOR-swizzle on 16B chunks
      asm volatile("s_waitcnt lgkmcnt(0)" ::: "memory");  // WAR vs previous read
#pragma unroll
      for (int kks = 0; kks < 2; kks++)
#pragma unroll
        for (int r = 0; r < 4; r++) {
          int row = 4 * g + r, col = kks * 16 + li;
          int ch = (col >> 3) ^ ((row >> 2) & 3);
          pw[row * 32 + ch * 8 + (col & 7)] = f2b(pv[kks][r]);
        }
      asm volatile("s_waitcnt lgkmcnt(0)" ::: "memory");  // RAW: writes visible
      int chr = g ^ ((li >> 2) & 3);
      v8s pa = *reinterpret_cast<v8s*>(&pw[li * 32 + chr * 8]);
#pragma unroll
      for (int ni = 0; ni < 4; ni++)
#pragma unroll
        for (int r = 0; r < 4; r++) o[ff][ni][r] *= al[r];
      const u16* vbase = vt + ((size_t)(ff * 32 + bh) * NDH) * NS;
#pragma unroll
      for (int ni = 0; ni < 4; ni++) {
        v8s vb = *reinterpret_cast<const v8s*>(vbase + (size_t)(ni * 16 + li) * NS + k0 + g * 8);
        o[ff][ni] = __builtin_amdgcn_mfma_f32_16x16x32_bf16(pa, vb, o[ff][ni], 0, 0, 0);
      }
    }
  }
  int b = bh >> 3;
#pragma unroll
  for (int ff = 0; ff < 3; ff++)
#pragma unroll
    for (int r = 0; r < 4; r++) {
      float l = lr[ff][r];
      l += __shfl_xor(l, 1);
      l += __shfl_xor(l, 2);
      l += __shfl_xor(l, 4);
      l += __shfl_xor(l, 8);
      lr[ff][r] = gates[ff] / l;
    }
#pragma unroll
  for (int ni = 0; ni < 4; ni++)
#pragma unroll
    for (int r = 0; r < 4; r++) {
      float v = o[0][ni][r] * lr[0][r] + o[1][ni][r] * lr[1][r] + o[2][ni][r] * lr[2][r];
      attno[((size_t)(b * NS + qw + 4 * g + r)) * ND + h * NDH + ni * 16 + li] = f2b(v);
    }
}

extern "C" void kernel_launch(void* const* d_in, const int* in_sizes, int n_in,
                              void* d_out, int out_size, void* d_ws, size_t ws_size,
                              hipStream_t stream) {
  const float* x0 = (const float*)d_in[0];
  const float* v0 = (const float*)d_in[1];
  const float* cf = (const float*)d_in[2];
  const float* qd = (const float*)d_in[3];
  const float* Wq = (const float*)d_in[4];
  const float* bq = (const float*)d_in[5];
  const float* Wkv = (const float*)d_in[6];
  const float* bkv = (const float*)d_in[7];
  const float* Wo = (const float*)d_in[8];
  const float* bo = (const float*)d_in[9];
  const float* fw = (const float*)d_in[10];
  const float* dnm = (const float*)d_in[11];
  const float* W1 = (const float*)d_in[12];
  const float* b1 = (const float*)d_in[13];
  const float* W2 = (const float*)d_in[14];
  const float* b2 = (const float*)d_in[15];
  const float* W3 = (const float*)d_in[16];
  const float* b3 = (const float*)d_in[17];

  char* ws = (char*)d_ws;
  size_t off = 0;
  auto alloc = [&](size_t bytes) -> void* {
    void* p = ws + off;
    off = (off + bytes + 255) & ~(size_t)255;
    return p;
  };
  const size_t E = 4096ull * 512;  // 2M elements per (B*S, D) tensor
  u16* Aq = (u16*)alloc(E * 2);
  u16* Af = (u16*)alloc(3 * E * 2);
  u16* Wqt = (u16*)alloc(262144ull * 2);
  u16* Wkvt = (u16*)alloc(3ull * 524288 * 2);
  u16* Wot = (u16*)alloc(262144ull * 2);
  float* crd = (float*)alloc(4096ull * 3 * 4);
  u16* qr = (u16*)alloc(E * 2);
  u16* kr = (u16*)alloc(3 * E * 2);
  u16* vtr = (u16*)alloc(3 * E * 2);
  u16* biasT = (u16*)alloc(33554432ull * 2);
  u16* attno = (u16*)alloc(E * 2);
  (void)ws_size; (void)in_sizes; (void)n_in; (void)out_size;

  cast_kernel<<<1024, 256, 0, stream>>>(qd, Aq, 262144);
  cast_kernel<<<1024, 256, 0, stream>>>(x0, Af, 262144);
  cast_kernel<<<1024, 256, 0, stream>>>(v0, Af + E, 262144);
  cast_kernel<<<1024, 256, 0, stream>>>(cf, Af + 2 * E, 262144);
  coords_kernel<<<16, 256, 0, stream>>>(x0, crd, 4096);
  dim3 tg1(16, 16);
  transpose_cast_kernel<<<tg1, 256, 0, stream>>>(Wq, Wqt, 512, 512);
  dim3 tg2(32, 16);
  for (int f = 0; f < 3; f++)
    transpose_cast_kernel<<<tg2, 256, 0, stream>>>(Wkv + (size_t)f * 524288,
                                                   Wkvt + (size_t)f * 524288, 512, 1024);
  transpose_cast_kernel<<<tg1, 256, 0, stream>>>(Wo, Wot, 512, 512);

  gemm_kernel<<<512, 256, 0, stream>>>(Aq, Wqt, bq, qr, nullptr, nullptr,
                                       4096, 512, 512, 0, 0);
  for (int f = 0; f < 3; f++)
    gemm_kernel<<<1024, 256, 0, stream>>>(Af + (size_t)f * E, Wkvt + (size_t)f * 524288,
                                          bkv + f * 1024, kr, vtr, nullptr,
                                          4096, 1024, 512, 1, f);
  bias_kernel<<<16384, 256, 0, stream>>>(crd, W1, b1, W2, b2, W3, b3, biasT);
  attn_kernel<<<512, 256, 0, stream>>>(qr, kr, vtr, biasT, fw, dnm, attno);
  gemm_kernel<<<512, 256, 0, stream>>>(attno, Wot, bo, nullptr, nullptr, (float*)d_out,
                                       4096, 512, 512, 2, 0);
}